// Round 1
// baseline (249.954 us; speedup 1.0000x reference)
//
#include <hip/hip_runtime.h>
#include <hip/hip_bf16.h>
#include <math.h>

// Problem constants (from reference setup): b=4, c=128, h=16, w=16
//   D  = 128*16*16 = 32768 floats per (n,b) slice
//   D4 = D/4 = 8192 float4 per slice
//   ITEM = b*D = 131072 floats per memory item
#define BQ   4
#define DIM  32768
#define DIM4 8192
#define ITEM4 32768   // (4*32768)/4 float4 per memory item
#define EPS  1e-8f

// ---------------- Kernel A: query norm^2 per batch row ----------------
__global__ void qnorm_kernel(const float* __restrict__ q, float* __restrict__ qn2) {
    const int b = blockIdx.x;
    const float4* q4 = (const float4*)(q + (size_t)b * DIM);
    float nrm = 0.f;
    for (int i = threadIdx.x; i < DIM4; i += blockDim.x) {
        float4 v = q4[i];
        nrm += v.x * v.x + v.y * v.y + v.z * v.z + v.w * v.w;
    }
    for (int off = 32; off > 0; off >>= 1) nrm += __shfl_down(nrm, off);
    __shared__ float s[8];
    const int wid = threadIdx.x >> 6;
    if ((threadIdx.x & 63) == 0) s[wid] = nrm;
    __syncthreads();
    if (threadIdx.x == 0) {
        float tot = 0.f;
        for (int w = 0; w < (int)(blockDim.x >> 6); ++w) tot += s[w];
        qn2[b] = tot;
    }
}

// ---------------- Kernel B: per-(n,b) dot(q,m) and ||m||^2 ----------------
__global__ void dot_norm_kernel(const float* __restrict__ q,
                                const float* __restrict__ mem,
                                float* __restrict__ dotv,
                                float* __restrict__ mn2v) {
    const int pair = blockIdx.x;        // n*4 + b
    const int b = pair & 3;
    const float4* q4 = (const float4*)(q + (size_t)b * DIM);
    const float4* m4 = (const float4*)(mem + (size_t)pair * DIM);
    float dot = 0.f, nrm = 0.f;
    for (int i = threadIdx.x; i < DIM4; i += blockDim.x) {
        float4 a = q4[i];
        float4 m = m4[i];
        dot += a.x * m.x + a.y * m.y + a.z * m.z + a.w * m.w;
        nrm += m.x * m.x + m.y * m.y + m.z * m.z + m.w * m.w;
    }
    for (int off = 32; off > 0; off >>= 1) {
        dot += __shfl_down(dot, off);
        nrm += __shfl_down(nrm, off);
    }
    __shared__ float sd[8], sn[8];
    const int wid = threadIdx.x >> 6;
    if ((threadIdx.x & 63) == 0) { sd[wid] = dot; sn[wid] = nrm; }
    __syncthreads();
    if (threadIdx.x == 0) {
        float d = 0.f, n2 = 0.f;
        for (int w = 0; w < (int)(blockDim.x >> 6); ++w) { d += sd[w]; n2 += sn[w]; }
        dotv[pair] = d;
        mn2v[pair] = n2;
    }
}

// ---------------- Kernel C: sims -> top-k -> softmax ----------------
__global__ void topk_softmax_kernel(const float* __restrict__ qn2,
                                    const float* __restrict__ dotv,
                                    const float* __restrict__ mn2v,
                                    const int* __restrict__ kp,
                                    float* __restrict__ weights,
                                    int* __restrict__ topidx,
                                    int N) {
    const int k = *kp;
    __shared__ float sims[2048];
    __shared__ float rvals[256];
    __shared__ int   ridx[256];
    __shared__ float qden[BQ];
    __shared__ float tvals[64];
    __shared__ int   tidxs[64];

    if (threadIdx.x < BQ) qden[threadIdx.x] = fmaxf(sqrtf(qn2[threadIdx.x]), EPS);
    __syncthreads();

    for (int n = threadIdx.x; n < N; n += blockDim.x) {
        float s = 0.f;
        #pragma unroll
        for (int b = 0; b < BQ; ++b) {
            float d  = dotv[n * BQ + b];
            float md = fmaxf(sqrtf(mn2v[n * BQ + b]), EPS);
            s += d / (qden[b] * md);
        }
        sims[n] = s * (1.0f / BQ);
    }
    __syncthreads();

    for (int it = 0; it < k; ++it) {
        float best = -INFINITY;
        int bidx = 0x7fffffff;
        for (int n = threadIdx.x; n < N; n += blockDim.x) {
            float v = sims[n];
            if (v > best || (v == best && n < bidx)) { best = v; bidx = n; }
        }
        rvals[threadIdx.x] = best;
        ridx[threadIdx.x]  = bidx;
        __syncthreads();
        for (int off = 128; off > 0; off >>= 1) {
            if ((int)threadIdx.x < off) {
                float v1 = rvals[threadIdx.x],      v2 = rvals[threadIdx.x + off];
                int   i1 = ridx[threadIdx.x],       i2 = ridx[threadIdx.x + off];
                if (v2 > v1 || (v2 == v1 && i2 < i1)) { rvals[threadIdx.x] = v2; ridx[threadIdx.x] = i2; }
            }
            __syncthreads();
        }
        if (threadIdx.x == 0) {
            tvals[it] = rvals[0];
            tidxs[it] = ridx[0];
            sims[ridx[0]] = -INFINITY;   // exclude for next round
        }
        __syncthreads();
    }

    if (threadIdx.x == 0) {
        float m = tvals[0];              // descending order: first is max
        float sum = 0.f;
        for (int i = 0; i < k; ++i) sum += expf(tvals[i] - m);
        float inv = 1.0f / sum;
        for (int i = 0; i < k; ++i) {
            weights[i] = expf(tvals[i] - m) * inv;
            topidx[i]  = tidxs[i];
        }
    }
}

// ---------------- Kernel D: weighted gather-sum of selected items ----------------
__global__ void wsum_kernel(const float* __restrict__ mem,
                            const float* __restrict__ weights,
                            const int* __restrict__ topidx,
                            const int* __restrict__ kp,
                            float* __restrict__ out) {
    const int k = *kp;
    __shared__ float w[64];
    __shared__ int   id[64];
    if ((int)threadIdx.x < k) {
        w[threadIdx.x]  = weights[threadIdx.x];
        id[threadIdx.x] = topidx[threadIdx.x];
    }
    __syncthreads();
    const int t = blockIdx.x * blockDim.x + threadIdx.x;   // float4 index within item
    if (t >= ITEM4) return;
    const float4* m4 = (const float4*)mem;
    float4 acc = {0.f, 0.f, 0.f, 0.f};
    for (int j = 0; j < k; ++j) {
        float4 v = m4[(size_t)id[j] * ITEM4 + t];
        float wj = w[j];
        acc.x += wj * v.x; acc.y += wj * v.y; acc.z += wj * v.z; acc.w += wj * v.w;
    }
    ((float4*)out)[t] = acc;
}

extern "C" void kernel_launch(void* const* d_in, const int* in_sizes, int n_in,
                              void* d_out, int out_size, void* d_ws, size_t ws_size,
                              hipStream_t stream) {
    const float* q   = (const float*)d_in[0];   // [4,128,16,16]
    const float* mem = (const float*)d_in[1];   // [N,4,128,16,16]
    const int*   kp  = (const int*)d_in[2];     // scalar k
    float* out = (float*)d_out;

    const int N = in_sizes[1] / (BQ * DIM);     // 2000

    // Workspace layout (floats):
    float* qn2  = (float*)d_ws;     // 4   (padded to 8)
    float* dotv = qn2 + 8;          // N*4
    float* mn2  = dotv + N * BQ;    // N*4
    float* wts  = mn2 + N * BQ;     // 64
    int*   tidx = (int*)(wts + 64); // 64

    qnorm_kernel<<<BQ, 256, 0, stream>>>(q, qn2);
    dot_norm_kernel<<<N * BQ, 256, 0, stream>>>(q, mem, dotv, mn2);
    topk_softmax_kernel<<<1, 256, 0, stream>>>(qn2, dotv, mn2, kp, wts, tidx, N);
    wsum_kernel<<<(ITEM4 + 255) / 256, 256, 0, stream>>>(mem, wts, tidx, kp, out);
}

// Round 2
// 230.550 us; speedup vs baseline: 1.0842x; 1.0842x over previous
//
#include <hip/hip_runtime.h>
#include <hip/hip_bf16.h>
#include <math.h>

// Problem constants (from reference setup): b=4, c=128, h=16, w=16
//   D    = 128*16*16 = 32768 floats per (n,b) slice
//   DIM4 = D/4 = 8192 float4 per slice
#define BQ    4
#define DIM   32768
#define DIM4  8192
#define ITEM4 32768   // (4*32768)/4 float4 per memory item
#define EPS   1e-8f

// ---------------- Kernel A: query norm^2 per batch row ----------------
__global__ void qnorm_kernel(const float* __restrict__ q, float* __restrict__ qn2) {
    const int b = blockIdx.x;
    const float4* q4 = (const float4*)(q + (size_t)b * DIM);
    float nrm = 0.f;
    for (int i = threadIdx.x; i < DIM4; i += blockDim.x) {
        float4 v = q4[i];
        nrm += v.x * v.x + v.y * v.y + v.z * v.z + v.w * v.w;
    }
    for (int off = 32; off > 0; off >>= 1) nrm += __shfl_down(nrm, off);
    __shared__ float s[16];
    const int wid = threadIdx.x >> 6;
    if ((threadIdx.x & 63) == 0) s[wid] = nrm;
    __syncthreads();
    if (threadIdx.x == 0) {
        float tot = 0.f;
        for (int w = 0; w < (int)(blockDim.x >> 6); ++w) tot += s[w];
        qn2[b] = tot;
    }
}

// ---------------- Kernel B: per-(n,b) dot(q,m) and ||m||^2 ----------------
// Each block is pinned to one batch row b; its 128 KB query slice lives in
// registers (16 float4/thread x 512 threads). Grid-strides over n, streaming
// only the memory bank from HBM (1 load per 16 B of HBM data).
#define QREG 16
__global__ __launch_bounds__(512) void dot_norm_kernel(
        const float* __restrict__ q, const float* __restrict__ mem,
        float* __restrict__ dotv, float* __restrict__ mn2v, int N) {
    const int b    = blockIdx.x & 3;
    const int bn   = blockIdx.x >> 2;       // block index within this b
    const int nblk = gridDim.x >> 2;        // blocks per b

    const float4* q4 = (const float4*)(q + (size_t)b * DIM);
    float4 qr[QREG];
    #pragma unroll
    for (int j = 0; j < QREG; ++j) qr[j] = q4[threadIdx.x + j * 512];

    __shared__ float sd[8], sn[8];

    for (int n = bn; n < N; n += nblk) {
        const float4* m4 = (const float4*)(mem + ((size_t)n * BQ + b) * DIM);
        float dot = 0.f, nrm = 0.f;
        #pragma unroll
        for (int j = 0; j < QREG; ++j) {
            float4 m = m4[threadIdx.x + j * 512];
            float4 a = qr[j];
            dot += a.x * m.x + a.y * m.y + a.z * m.z + a.w * m.w;
            nrm += m.x * m.x + m.y * m.y + m.z * m.z + m.w * m.w;
        }
        for (int off = 32; off > 0; off >>= 1) {
            dot += __shfl_down(dot, off);
            nrm += __shfl_down(nrm, off);
        }
        const int wid = threadIdx.x >> 6;
        if ((threadIdx.x & 63) == 0) { sd[wid] = dot; sn[wid] = nrm; }
        __syncthreads();
        if (threadIdx.x == 0) {
            float d = 0.f, n2 = 0.f;
            #pragma unroll
            for (int w = 0; w < 8; ++w) { d += sd[w]; n2 += sn[w]; }
            dotv[n * BQ + b] = d;
            mn2v[n * BQ + b] = n2;
        }
        __syncthreads();   // sd/sn reused next iteration
    }
}

// ---------------- Kernel C: sims -> top-k -> softmax ----------------
__global__ void topk_softmax_kernel(const float* __restrict__ qn2,
                                    const float* __restrict__ dotv,
                                    const float* __restrict__ mn2v,
                                    const int* __restrict__ kp,
                                    float* __restrict__ weights,
                                    int* __restrict__ topidx,
                                    int N) {
    const int k = *kp;
    __shared__ float sims[2048];
    __shared__ float swv[4];
    __shared__ int   swi[4];
    __shared__ float qden[BQ];
    __shared__ float tvals[64];
    __shared__ int   tidxs[64];

    if (threadIdx.x < BQ) qden[threadIdx.x] = fmaxf(sqrtf(qn2[threadIdx.x]), EPS);
    __syncthreads();

    for (int n = threadIdx.x; n < N; n += blockDim.x) {
        float s = 0.f;
        #pragma unroll
        for (int b = 0; b < BQ; ++b) {
            float d  = dotv[n * BQ + b];
            float md = fmaxf(sqrtf(mn2v[n * BQ + b]), EPS);
            s += d / (qden[b] * md);
        }
        sims[n] = s * (1.0f / BQ);
    }
    __syncthreads();

    const int lane = threadIdx.x & 63;
    const int wid  = threadIdx.x >> 6;

    for (int it = 0; it < k; ++it) {
        float best = -INFINITY;
        int bidx = 0x7fffffff;
        for (int n = threadIdx.x; n < N; n += blockDim.x) {
            float v = sims[n];
            if (v > best || (v == best && n < bidx)) { best = v; bidx = n; }
        }
        // wave-level argmax reduce (lowest-index tie-break), no barriers
        for (int off = 32; off > 0; off >>= 1) {
            float ov = __shfl_down(best, off);
            int   oi = __shfl_down(bidx, off);
            if (ov > best || (ov == best && oi < bidx)) { best = ov; bidx = oi; }
        }
        if (lane == 0) { swv[wid] = best; swi[wid] = bidx; }
        __syncthreads();
        if (threadIdx.x == 0) {
            float bv = swv[0]; int bi = swi[0];
            #pragma unroll
            for (int w = 1; w < 4; ++w) {
                if (swv[w] > bv || (swv[w] == bv && swi[w] < bi)) { bv = swv[w]; bi = swi[w]; }
            }
            tvals[it] = bv;
            tidxs[it] = bi;
            sims[bi]  = -INFINITY;   // exclude for next round
        }
        __syncthreads();
    }

    if (threadIdx.x == 0) {
        float m = tvals[0];          // descending: first is the max
        float sum = 0.f;
        for (int i = 0; i < k; ++i) sum += expf(tvals[i] - m);
        float inv = 1.0f / sum;
        for (int i = 0; i < k; ++i) {
            weights[i] = expf(tvals[i] - m) * inv;
            topidx[i]  = tidxs[i];
        }
    }
}

// ---------------- Kernel D: weighted gather-sum of selected items ----------------
__global__ void wsum_kernel(const float* __restrict__ mem,
                            const float* __restrict__ weights,
                            const int* __restrict__ topidx,
                            const int* __restrict__ kp,
                            float* __restrict__ out) {
    const int k = *kp;
    __shared__ float w[64];
    __shared__ int   id[64];
    if ((int)threadIdx.x < k) {
        w[threadIdx.x]  = weights[threadIdx.x];
        id[threadIdx.x] = topidx[threadIdx.x];
    }
    __syncthreads();
    const int t = blockIdx.x * blockDim.x + threadIdx.x;   // float4 index within item
    if (t >= ITEM4) return;
    const float4* m4 = (const float4*)mem;
    float4 acc = {0.f, 0.f, 0.f, 0.f};
    for (int j = 0; j < k; ++j) {
        float4 v = m4[(size_t)id[j] * ITEM4 + t];
        float wj = w[j];
        acc.x += wj * v.x; acc.y += wj * v.y; acc.z += wj * v.z; acc.w += wj * v.w;
    }
    ((float4*)out)[t] = acc;
}

extern "C" void kernel_launch(void* const* d_in, const int* in_sizes, int n_in,
                              void* d_out, int out_size, void* d_ws, size_t ws_size,
                              hipStream_t stream) {
    const float* q   = (const float*)d_in[0];   // [4,128,16,16]
    const float* mem = (const float*)d_in[1];   // [N,4,128,16,16]
    const int*   kp  = (const int*)d_in[2];     // scalar k
    float* out = (float*)d_out;

    const int N = in_sizes[1] / (BQ * DIM);     // 2000

    // Workspace layout (floats):
    float* qn2  = (float*)d_ws;     // 4   (padded to 8)
    float* dotv = qn2 + 8;          // N*4
    float* mn2  = dotv + N * BQ;    // N*4
    float* wts  = mn2 + N * BQ;     // 64
    int*   tidx = (int*)(wts + 64); // 64

    qnorm_kernel<<<BQ, 256, 0, stream>>>(q, qn2);
    dot_norm_kernel<<<2048, 512, 0, stream>>>(q, mem, dotv, mn2, N);
    topk_softmax_kernel<<<1, 256, 0, stream>>>(qn2, dotv, mn2, kp, wts, tidx, N);
    wsum_kernel<<<512, 64, 0, stream>>>(mem, wts, tidx, kp, out);
}